// Round 1
// baseline (360.272 us; speedup 1.0000x reference)
//
#include <hip/hip_runtime.h>

typedef _Float16 half8 __attribute__((ext_vector_type(8)));
typedef float f32x4 __attribute__((ext_vector_type(4)));

static __device__ __forceinline__ f32x4 mfma16(half8 a, half8 b, f32x4 c) {
    return __builtin_amdgcn_mfma_f32_16x16x32_f16(a, b, c, 0, 0, 0);
}

// ---------------------------------------------------------------------------
// f32 -> f16 conversion, 8 elems/thread
// ---------------------------------------------------------------------------
__global__ void __launch_bounds__(256) f32_to_f16(const float* __restrict__ in,
                                                  _Float16* __restrict__ out, int n) {
    long i = ((long)blockIdx.x * 256 + threadIdx.x) * 8;
    if (i >= n) return;
    f32x4 v0 = *(const f32x4*)(in + i);
    f32x4 v1 = *(const f32x4*)(in + i + 4);
    half8 h;
#pragma unroll
    for (int j = 0; j < 4; j++) { h[j] = (_Float16)v0[j]; h[4 + j] = (_Float16)v1[j]; }
    *(half8*)(out + i) = h;
}

// ---------------------------------------------------------------------------
// GEMM: C[M,N] = A[M,K] @ Bw[N,K]^T + bias (+relu / +resid, f32 out)
// MODE 0: f16 out.  MODE 1: f16 out + relu.  MODE 2: f32 out + f32 residual.
// 128x128 tile, BK=32, 256 threads = 4 waves (2x2), 64x64 per wave (4x4 frags)
// ---------------------------------------------------------------------------
template <int MODE>
__global__ void __launch_bounds__(256) gemm_bt(const _Float16* __restrict__ A,
                                               const _Float16* __restrict__ Bw,
                                               const float* __restrict__ bias,
                                               const float* __restrict__ resid,
                                               void* __restrict__ Cout,
                                               int M, int N, int K) {
    __shared__ __align__(16) _Float16 As[128 * 32];
    __shared__ __align__(16) _Float16 Bs[128 * 32];
    const int tid = threadIdx.x;
    const int lane = tid & 63;
    const int w = tid >> 6;
    const int g = lane >> 4, l15 = lane & 15;
    const int wm = w >> 1, wn = w & 1;
    const long rowblk = (long)blockIdx.y * 128;
    const long colblk = (long)blockIdx.x * 128;

    const int srow = tid >> 2;          // 0..63
    const int scol = (tid & 3) * 8;     // 0,8,16,24
    const _Float16* Ap = A + (rowblk + srow) * (long)K + scol;
    const _Float16* Bp = Bw + (colblk + srow) * (long)K + scol;
    const long halfK = 64L * K;

    f32x4 zero = {0.f, 0.f, 0.f, 0.f};
    f32x4 acc[4][4];
#pragma unroll
    for (int i = 0; i < 4; i++)
#pragma unroll
        for (int j = 0; j < 4; j++) acc[i][j] = zero;

    for (int k0 = 0; k0 < K; k0 += 32) {
        half8 a1 = *(const half8*)(Ap + k0);
        half8 a2 = *(const half8*)(Ap + halfK + k0);
        half8 b1 = *(const half8*)(Bp + k0);
        half8 b2 = *(const half8*)(Bp + halfK + k0);
        __syncthreads();  // previous iter frag reads complete
        *(half8*)(As + tid * 8) = a1;
        *(half8*)(As + 2048 + tid * 8) = a2;
        *(half8*)(Bs + tid * 8) = b1;
        *(half8*)(Bs + 2048 + tid * 8) = b2;
        __syncthreads();
        half8 af[4], bf[4];
#pragma unroll
        for (int mi = 0; mi < 4; mi++)
            af[mi] = *(const half8*)(As + (wm * 64 + mi * 16 + l15) * 32 + g * 8);
#pragma unroll
        for (int ni = 0; ni < 4; ni++)
            bf[ni] = *(const half8*)(Bs + (wn * 64 + ni * 16 + l15) * 32 + g * 8);
#pragma unroll
        for (int mi = 0; mi < 4; mi++)
#pragma unroll
            for (int ni = 0; ni < 4; ni++)
                acc[mi][ni] = mfma16(af[mi], bf[ni], acc[mi][ni]);
    }

    const long crow0 = rowblk + wm * 64 + g * 4;
    const long ccol0 = colblk + wn * 64 + l15;
#pragma unroll
    for (int mi = 0; mi < 4; mi++) {
#pragma unroll
        for (int ni = 0; ni < 4; ni++) {
            const long cc = ccol0 + ni * 16;
            const float bv = bias[cc];
#pragma unroll
            for (int r = 0; r < 4; r++) {
                const long rr = crow0 + mi * 16 + r;
                float v = acc[mi][ni][r] + bv;
                if (MODE == 1) v = fmaxf(v, 0.f);
                if (MODE == 2) {
                    ((float*)Cout)[rr * N + cc] = v + resid[rr * N + cc];
                } else {
                    ((_Float16*)Cout)[rr * N + cc] = (_Float16)v;
                }
            }
        }
    }
}

// ---------------------------------------------------------------------------
// Build V^T: vt[bh][d][t] from qkv (V at channel offset 1024)
// grid (8, 32), 256 threads; wave w handles 64-token chunk
// ---------------------------------------------------------------------------
__global__ void __launch_bounds__(256) build_vt(const _Float16* __restrict__ qkv,
                                                _Float16* __restrict__ vt) {
    const int tid = threadIdx.x, lane = tid & 63, w = tid >> 6;
    const int bh = blockIdx.y, b = bh >> 3, h = bh & 7;
    const int tc = blockIdx.x * 4 + w;  // 0..31
    const int d = lane;
#pragma unroll
    for (int jj = 0; jj < 8; jj++) {
        half8 buf;
#pragma unroll
        for (int j = 0; j < 8; j++) {
            int t = tc * 64 + jj * 8 + j;
            buf[j] = qkv[(long)(t * 4 + b) * 1536 + 1024 + h * 64 + d];
        }
        *(half8*)(vt + (long)(bh * 64 + d) * 2048 + tc * 64 + jj * 8) = buf;
    }
}

// ---------------------------------------------------------------------------
// Flash attention: grid (16, 32), 256 threads = 4 waves, wave owns 32 q-rows.
// Q in regs; K frags from global (L2); P via per-wave LDS; V^T frags from vt.
// ---------------------------------------------------------------------------
__global__ void __launch_bounds__(256) attn_fwd(const _Float16* __restrict__ qkv,
                                                const _Float16* __restrict__ vt,
                                                _Float16* __restrict__ attn_out) {
    __shared__ __align__(16) _Float16 Plds[4][32 * 72];
    const int tid = threadIdx.x;
    const int lane = tid & 63;
    const int w = tid >> 6;
    const int g = lane >> 4, l15 = lane & 15;
    const int bh = blockIdx.y;
    const int b = bh >> 3, h = bh & 7;
    const int s0 = blockIdx.x * 128 + w * 32;
    const int qoff = h * 64;

    half8 qa[2][2];
#pragma unroll
    for (int mi = 0; mi < 2; mi++)
#pragma unroll
        for (int ks = 0; ks < 2; ks++) {
            long row = (long)((s0 + mi * 16 + l15) * 4 + b) * 1536;
            qa[mi][ks] = *(const half8*)(qkv + row + qoff + ks * 32 + g * 8);
        }

    f32x4 zero = {0.f, 0.f, 0.f, 0.f};
    f32x4 o[2][4];
    float mst[2][4], lst[2][4];
#pragma unroll
    for (int mi = 0; mi < 2; mi++) {
#pragma unroll
        for (int di = 0; di < 4; di++) o[mi][di] = zero;
#pragma unroll
        for (int r = 0; r < 4; r++) { mst[mi][r] = -1e30f; lst[mi][r] = 0.f; }
    }

    for (int t0 = 0; t0 < 2048; t0 += 64) {
        f32x4 sa[2][4];
#pragma unroll
        for (int mi = 0; mi < 2; mi++)
#pragma unroll
            for (int ni = 0; ni < 4; ni++) sa[mi][ni] = zero;

#pragma unroll
        for (int ni = 0; ni < 4; ni++)
#pragma unroll
            for (int ks = 0; ks < 2; ks++) {
                long row = (long)((t0 + ni * 16 + l15) * 4 + b) * 1536;
                half8 kb = *(const half8*)(qkv + row + 512 + qoff + ks * 32 + g * 8);
                sa[0][ni] = mfma16(qa[0][ks], kb, sa[0][ni]);
                sa[1][ni] = mfma16(qa[1][ks], kb, sa[1][ni]);
            }

        // scale 1/sqrt(64)
#pragma unroll
        for (int mi = 0; mi < 2; mi++)
#pragma unroll
            for (int ni = 0; ni < 4; ni++)
#pragma unroll
                for (int r = 0; r < 4; r++) sa[mi][ni][r] *= 0.125f;

        float corr[2][4];
#pragma unroll
        for (int mi = 0; mi < 2; mi++)
#pragma unroll
            for (int r = 0; r < 4; r++) {
                float mx = fmaxf(fmaxf(sa[mi][0][r], sa[mi][1][r]),
                                 fmaxf(sa[mi][2][r], sa[mi][3][r]));
                mx = fmaxf(mx, __shfl_xor(mx, 1));
                mx = fmaxf(mx, __shfl_xor(mx, 2));
                mx = fmaxf(mx, __shfl_xor(mx, 4));
                mx = fmaxf(mx, __shfl_xor(mx, 8));
                float mnew = fmaxf(mst[mi][r], mx);
                float c = __expf(mst[mi][r] - mnew);
                corr[mi][r] = c;
                mst[mi][r] = mnew;
                float rs = 0.f;
#pragma unroll
                for (int ni = 0; ni < 4; ni++) {
                    float p = __expf(sa[mi][ni][r] - mnew);
                    sa[mi][ni][r] = p;
                    rs += p;
                }
                rs += __shfl_xor(rs, 1);
                rs += __shfl_xor(rs, 2);
                rs += __shfl_xor(rs, 4);
                rs += __shfl_xor(rs, 8);
                lst[mi][r] = lst[mi][r] * c + rs;
                const int prow = mi * 16 + g * 4 + r;
#pragma unroll
                for (int ni = 0; ni < 4; ni++)
                    Plds[w][prow * 72 + ni * 16 + l15] = (_Float16)sa[mi][ni][r];
            }

        // rescale O accumulators
#pragma unroll
        for (int mi = 0; mi < 2; mi++)
#pragma unroll
            for (int di = 0; di < 4; di++)
#pragma unroll
                for (int r = 0; r < 4; r++) o[mi][di][r] *= corr[mi][r];

        // P @ V  (same-wave LDS write->read: DS pipe in-order, no barrier needed)
        half8 pa[2][2];
#pragma unroll
        for (int mi = 0; mi < 2; mi++)
#pragma unroll
            for (int ks = 0; ks < 2; ks++)
                pa[mi][ks] = *(const half8*)&Plds[w][(mi * 16 + l15) * 72 + ks * 32 + g * 8];
#pragma unroll
        for (int di = 0; di < 4; di++)
#pragma unroll
            for (int ks = 0; ks < 2; ks++) {
                long vrow = (long)(bh * 64 + di * 16 + l15) * 2048;
                half8 vb = *(const half8*)(vt + vrow + t0 + ks * 32 + g * 8);
                o[0][di] = mfma16(pa[0][ks], vb, o[0][di]);
                o[1][di] = mfma16(pa[1][ks], vb, o[1][di]);
            }
    }

#pragma unroll
    for (int mi = 0; mi < 2; mi++)
#pragma unroll
        for (int r = 0; r < 4; r++) {
            float inv = 1.f / lst[mi][r];
            long srow = (long)((s0 + mi * 16 + g * 4 + r) * 4 + b) * 512;
#pragma unroll
            for (int di = 0; di < 4; di++)
                attn_out[srow + qoff + di * 16 + l15] = (_Float16)(o[mi][di][r] * inv);
        }
}

// ---------------------------------------------------------------------------
// LayerNorm over rows of 512; one wave per row; optional f16 copy of output
// ---------------------------------------------------------------------------
__global__ void __launch_bounds__(256) ln_rows(const float* __restrict__ in,
                                               const float* __restrict__ gamma,
                                               const float* __restrict__ beta,
                                               float* __restrict__ outf,
                                               _Float16* __restrict__ outh) {
    const int tid = threadIdx.x, lane = tid & 63, w = tid >> 6;
    const long row = (long)blockIdx.x * 4 + w;
    const float* p = in + row * 512 + lane * 8;
    f32x4 v0 = *(const f32x4*)p;
    f32x4 v1 = *(const f32x4*)(p + 4);
    float s = v0[0] + v0[1] + v0[2] + v0[3] + v1[0] + v1[1] + v1[2] + v1[3];
    float q = v0[0] * v0[0] + v0[1] * v0[1] + v0[2] * v0[2] + v0[3] * v0[3] +
              v1[0] * v1[0] + v1[1] * v1[1] + v1[2] * v1[2] + v1[3] * v1[3];
#pragma unroll
    for (int off = 1; off < 64; off <<= 1) {
        s += __shfl_xor(s, off);
        q += __shfl_xor(q, off);
    }
    const float mu = s * (1.0f / 512.0f);
    const float var = q * (1.0f / 512.0f) - mu * mu;
    const float rstd = rsqrtf(var + 1e-5f);
    const float* gp = gamma + lane * 8;
    const float* bp = beta + lane * 8;
    f32x4 g0 = *(const f32x4*)gp, g1 = *(const f32x4*)(gp + 4);
    f32x4 b0 = *(const f32x4*)bp, b1 = *(const f32x4*)(bp + 4);
    f32x4 o0, o1;
#pragma unroll
    for (int j = 0; j < 4; j++) {
        o0[j] = (v0[j] - mu) * rstd * g0[j] + b0[j];
        o1[j] = (v1[j] - mu) * rstd * g1[j] + b1[j];
    }
    float* op = outf + row * 512 + lane * 8;
    *(f32x4*)op = o0;
    *(f32x4*)(op + 4) = o1;
    if (outh) {
        half8 h;
#pragma unroll
        for (int j = 0; j < 4; j++) { h[j] = (_Float16)o0[j]; h[4 + j] = (_Float16)o1[j]; }
        *(half8*)(outh + row * 512 + lane * 8) = h;
    }
}

// ---------------------------------------------------------------------------
extern "C" void kernel_launch(void* const* d_in, const int* in_sizes, int n_in,
                              void* d_out, int out_size, void* d_ws, size_t ws_size,
                              hipStream_t stream) {
    const float* x    = (const float*)d_in[0];
    const float* inw  = (const float*)d_in[1];
    const float* inb  = (const float*)d_in[2];
    const float* outw = (const float*)d_in[3];
    const float* outb = (const float*)d_in[4];
    const float* g1   = (const float*)d_in[5];
    const float* b1   = (const float*)d_in[6];
    const float* f1w  = (const float*)d_in[7];
    const float* f1b  = (const float*)d_in[8];
    const float* f2w  = (const float*)d_in[9];
    const float* f2b  = (const float*)d_in[10];
    const float* g2   = (const float*)d_in[11];
    const float* b2   = (const float*)d_in[12];

    char* ws = (char*)d_ws;
    const long MB = 1024 * 1024;
    _Float16* X16  = (_Float16*)(ws + 0);       // 8 MB   (x f16)
    _Float16* QKV  = (_Float16*)(ws + 8 * MB);  // 24 MB
    _Float16* H16  = (_Float16*)(ws + 0);       // 32 MB  (reuses X16+QKV after attn)
    _Float16* VT   = (_Float16*)(ws + 32 * MB); // 8 MB
    _Float16* ATT  = (_Float16*)(ws + 40 * MB); // 8 MB
    float*    PRE  = (float*)(ws + 48 * MB);    // 16 MB  (pre-LN1, reused pre-LN2)
    float*    YF   = (float*)(ws + 64 * MB);    // 16 MB  (y f32)
    _Float16* Y16  = (_Float16*)(ws + 80 * MB); // 8 MB   (y f16)
    _Float16* WIN  = (_Float16*)(ws + 88 * MB); // 1.5 MB
    _Float16* WOUT = (_Float16*)(ws + 90 * MB); // 0.5 MB
    _Float16* WF1  = (_Float16*)(ws + 91 * MB); // 2 MB
    _Float16* WF2  = (_Float16*)(ws + 93 * MB); // 2 MB   (total 95 MB)

    // conversions
    f32_to_f16<<<2048, 256, 0, stream>>>(x, X16, 8192 * 512);
    f32_to_f16<<<384, 256, 0, stream>>>(inw, WIN, 1536 * 512);
    f32_to_f16<<<128, 256, 0, stream>>>(outw, WOUT, 512 * 512);
    f32_to_f16<<<512, 256, 0, stream>>>(f1w, WF1, 2048 * 512);
    f32_to_f16<<<512, 256, 0, stream>>>(f2w, WF2, 512 * 2048);

    // qkv projection
    gemm_bt<0><<<dim3(12, 64), 256, 0, stream>>>(X16, WIN, inb, nullptr, QKV, 8192, 1536, 512);
    // attention
    build_vt<<<dim3(8, 32), 256, 0, stream>>>(QKV, VT);
    attn_fwd<<<dim3(16, 32), 256, 0, stream>>>(QKV, VT, ATT);
    // out projection + residual -> pre-LN1
    gemm_bt<2><<<dim3(4, 64), 256, 0, stream>>>(ATT, WOUT, outb, x, PRE, 8192, 512, 512);
    ln_rows<<<2048, 256, 0, stream>>>(PRE, g1, b1, YF, Y16);
    // FFN
    gemm_bt<1><<<dim3(16, 64), 256, 0, stream>>>(Y16, WF1, f1b, nullptr, H16, 8192, 2048, 512);
    gemm_bt<2><<<dim3(4, 64), 256, 0, stream>>>(H16, WF2, f2b, YF, PRE, 8192, 512, 2048);
    ln_rows<<<2048, 256, 0, stream>>>(PRE, g2, b2, (float*)d_out, nullptr);
}